// Round 2
// baseline (5645.371 us; speedup 1.0000x reference)
//
#include <hip/hip_runtime.h>
#include <cstdint>
#include <cstddef>

// Problem constants
#define K_ 512
#define T_ 32768
#define L_STEPS 1024   // T_/32 chunks

// workspace layout (bytes) -- total ~26 MB
#define OFF_EHAT   0ul         // 512*512 fp8 = 262144
#define OFF_GPART  262144ul    // 32 f32 gold partials
#define OFF_SSCAL  262400ul    // 256 int slice scales
#define OFF_SC     263424ul    // 64 int: per-level mat scales (L0@0 x32, L1@32 x16, L2@48 x8, L3@56 x4, L4@60 x2, L5@62 x1)
#define OFF_MM     263680ul    // 64 uint: per-level mat maxima (f32 bit patterns), same sub-offsets
#define OFF_MATS_A 1048576ul   // 32 mats * 512*512 bf16 = 16777216
#define OFF_MATS_B 17825792ul  // 16 mats bf16 = 8388608 (end 26214400)

typedef float f32x4 __attribute__((ext_vector_type(4)));

static __device__ __forceinline__ unsigned short f2bf(float x) {
  unsigned u = __float_as_uint(x);
  u += 0x7fffu + ((u >> 16) & 1u);
  return (unsigned short)(u >> 16);
}
static __device__ __forceinline__ float bf2f(unsigned short h) {
  return __uint_as_float(((unsigned)h) << 16);
}

// ---------------- init: zero the atomic-max slots ----------------
__global__ __launch_bounds__(64) void init_k(unsigned* __restrict__ mm) {
  mm[threadIdx.x] = 0u;
}

// ---------------- prep: Ehat = fp8_e4m3(exp(transitions)) ----------------
__global__ __launch_bounds__(512) void prep_e8_k(const float* __restrict__ tr,
                                                 uint8_t* __restrict__ Ehat) {
  int gid = blockIdx.x * 512 + threadIdx.x;   // 131072 threads, 2 elems each
  int i2 = gid * 2;
  float a = fminf(__expf(tr[i2]), 440.f);
  float b = fminf(__expf(tr[i2 + 1]), 440.f);
  int w = __builtin_amdgcn_cvt_pk_fp8_f32(a, b, 0, false);
  *(unsigned short*)(Ehat + i2) = (unsigned short)(w & 0xffff);
}

// ---------------- gold score (exact f32, deterministic, 32 partials) ----------------
__global__ __launch_bounds__(1024) void gold_k(const float* __restrict__ obs,
                                               const int* __restrict__ tags,
                                               const float* __restrict__ tr,
                                               float* __restrict__ gpart) {
  __shared__ float red[1024];
  int i = blockIdx.x * 1024 + threadIdx.x;
  float s = 0.f;
  if (i < T_ - 1) {
    int cur = tags[i], nxt = tags[i + 1];
    s = tr[nxt * K_ + cur] + obs[(size_t)nxt * T_ + i];
  }
  red[threadIdx.x] = s;
  __syncthreads();
  for (int h = 512; h > 0; h >>= 1) {
    if ((int)threadIdx.x < h) red[threadIdx.x] += red[threadIdx.x + h];
    __syncthreads();
  }
  if (threadIdx.x == 0) gpart[blockIdx.x] = red[0];
}

// ---------------- phase 1: per-(chunk, 64-col slice) transfer matrix ----------------
// wg = 512 threads (8 waves). Wave w owns output rows 64w..64w+63; E rows resident
// as fp8 MFMA A-fragments (64 x i64 = 128 VGPR). P slice (512 x 64) lives in LDS
// transposed: PldsT[col][k], row stride 520 bytes. Per step:
//   acc = E * P  (16x16x32 fp8 MFMA, K-chain of 16)
//   val = acc * exp(o_t[row]); renorm so max is in [128,256) by power of 2; store fp8.
__global__ __launch_bounds__(512, 2)
void phase1_k(const uint8_t* __restrict__ Ehat, const float* __restrict__ obs,
              unsigned short* __restrict__ mats, int* __restrict__ sliceScales) {
  __shared__ __align__(16) uint8_t Plds[64 * 520];   // 33280 B
  __shared__ float obs_lds[8][512];                  // 16384 B
  __shared__ float wavemax[8];

  const int tid = threadIdx.x;
  const int wv = tid >> 6;
  const int lane = tid & 63;
  const int l15 = lane & 15;
  const int g = lane >> 4;
  const int chunk = blockIdx.x >> 3;
  const int slice = blockIdx.x & 7;

  // E fragments: lane holds A[row=l15 (+16rt+64wv)][k=8g..8g+7] per (row-tile, k-tile)
  long long ef[4][16];
#pragma unroll
  for (int rt = 0; rt < 4; ++rt)
#pragma unroll
    for (int kt = 0; kt < 16; ++kt)
      ef[rt][kt] = *(const long long*)(Ehat +
          ((64 * wv + 16 * rt + l15) * 512 + 32 * kt + 8 * g));

  // init P = identity slice
  for (int i = tid; i < 64 * 520 / 4; i += 512) ((int*)Plds)[i] = 0;
  __syncthreads();
  if (tid < 64) {
    int gj = slice * 64 + tid;          // global state index of this column
    Plds[tid * 520 + gj] = 0x38;        // fp8 e4m3 1.0
  }
  __syncthreads();

  int accScale = 0;
  const int t0 = chunk * L_STEPS;

#pragma unroll 1
  for (int tl = 0; tl < L_STEPS; ++tl) {
    if ((tl & 7) == 0) {
      // stage obs[:, t0+tl .. +7] transposed into LDS
      const float4* sp4 = (const float4*)(obs + (size_t)tid * T_ + (t0 + tl));
      float4 a0 = sp4[0], a1 = sp4[1];
      obs_lds[0][tid] = a0.x; obs_lds[1][tid] = a0.y;
      obs_lds[2][tid] = a0.z; obs_lds[3][tid] = a0.w;
      obs_lds[4][tid] = a1.x; obs_lds[5][tid] = a1.y;
      obs_lds[6][tid] = a1.z; obs_lds[7][tid] = a1.w;
      __syncthreads();
    }

    f32x4 acc[4][4];
#pragma unroll
    for (int rt = 0; rt < 4; ++rt)
#pragma unroll
      for (int ct = 0; ct < 4; ++ct) acc[rt][ct] = (f32x4){0.f, 0.f, 0.f, 0.f};

#pragma unroll
    for (int kt = 0; kt < 16; ++kt) {
      const uint8_t* pb = Plds + 32 * kt + 8 * g;
      long long b0 = *(const long long*)(pb + (l15)      * 520);
      long long b1 = *(const long long*)(pb + (16 + l15) * 520);
      long long b2 = *(const long long*)(pb + (32 + l15) * 520);
      long long b3 = *(const long long*)(pb + (48 + l15) * 520);
#pragma unroll
      for (int rt = 0; rt < 4; ++rt) {
        acc[rt][0] = __builtin_amdgcn_mfma_f32_16x16x32_fp8_fp8(ef[rt][kt], b0, acc[rt][0], 0, 0, 0);
        acc[rt][1] = __builtin_amdgcn_mfma_f32_16x16x32_fp8_fp8(ef[rt][kt], b1, acc[rt][1], 0, 0, 0);
        acc[rt][2] = __builtin_amdgcn_mfma_f32_16x16x32_fp8_fp8(ef[rt][kt], b2, acc[rt][2], 0, 0, 0);
        acc[rt][3] = __builtin_amdgcn_mfma_f32_16x16x32_fp8_fp8(ef[rt][kt], b3, acc[rt][3], 0, 0, 0);
      }
    }

    // epilogue: row scale by exp(o_t), power-of-2 renorm, fp8 store
    const int tl7 = tl & 7;
    float eo[4][4];
#pragma unroll
    for (int rt = 0; rt < 4; ++rt)
#pragma unroll
      for (int j = 0; j < 4; ++j)
        eo[rt][j] = __expf(obs_lds[tl7][64 * wv + 16 * rt + 4 * g + j]);

    float mx = 0.f;
#pragma unroll
    for (int rt = 0; rt < 4; ++rt)
#pragma unroll
      for (int ct = 0; ct < 4; ++ct)
#pragma unroll
        for (int j = 0; j < 4; ++j)
          mx = fmaxf(mx, acc[rt][ct][j] * eo[rt][j]);
#pragma unroll
    for (int off = 1; off < 64; off <<= 1) mx = fmaxf(mx, __shfl_xor(mx, off, 64));
    if (lane == 0) wavemax[wv] = mx;
    __syncthreads();   // also: all P reads (B-frags) complete before overwrite

    float m8 = wavemax[0];
#pragma unroll
    for (int q = 1; q < 8; ++q) m8 = fmaxf(m8, wavemax[q]);
    int ebits = (int)((__float_as_uint(m8) >> 23) & 255) - 127;
    int s = 7 - ebits;
    if (s < -120) s = -120;
    if (s > 120) s = 120;
    float scale = __uint_as_float((unsigned)(127 + s) << 23);
    accScale -= s;     // TRUE = stored * 2^accScale

#pragma unroll
    for (int rt = 0; rt < 4; ++rt)
#pragma unroll
      for (int ct = 0; ct < 4; ++ct) {
        float v0 = acc[rt][ct][0] * eo[rt][0] * scale;
        float v1 = acc[rt][ct][1] * eo[rt][1] * scale;
        float v2 = acc[rt][ct][2] * eo[rt][2] * scale;
        float v3 = acc[rt][ct][3] * eo[rt][3] * scale;
        int w32 = __builtin_amdgcn_cvt_pk_fp8_f32(v0, v1, 0, false);
        w32 = __builtin_amdgcn_cvt_pk_fp8_f32(v2, v3, w32, true);
        // rows 4 consecutive (4g..4g+3), col = 16ct+l15
        *(int*)(Plds + (16 * ct + l15) * 520 + (64 * wv + 16 * rt + 4 * g)) = w32;
      }
    __syncthreads();
  }

  // write slice (bf16) to chunk matrix, row-major [i][j]
  for (int cl = 0; cl < 64; ++cl) {
    float f = __builtin_amdgcn_cvt_f32_fp8((int)Plds[cl * 520 + tid], 0);
    mats[(size_t)chunk * 262144 + (size_t)tid * 512 + slice * 64 + cl] = f2bf(f);
  }
  if (tid == 0) sliceScales[blockIdx.x] = accScale;
}

// ---------------- repair: harmonize the 8 slice scales of each chunk; record chunk max ----------------
__global__ __launch_bounds__(256) void repair_k(unsigned short* __restrict__ mats,
                                                const int* __restrict__ sliceScales,
                                                int* __restrict__ chunkScales,
                                                unsigned* __restrict__ mmL0) {
  int chunk = blockIdx.x >> 3, slice = blockIdx.x & 7;
  int smax = sliceScales[chunk * 8];
  for (int q = 1; q < 8; ++q) smax = max(smax, sliceScales[chunk * 8 + q]);
  int d = sliceScales[chunk * 8 + slice] - smax;   // <= 0
  float fac = exp2f((float)max(d, -126));
  float lmax = 0.f;
  for (int n = threadIdx.x; n < 512 * 64; n += 256) {
    int row = n >> 6, col = n & 63;
    size_t idx = (size_t)chunk * 262144 + (size_t)row * 512 + slice * 64 + col;
    float v = bf2f(mats[idx]) * fac;
    mats[idx] = f2bf(v);
    lmax = fmaxf(lmax, v);
  }
#pragma unroll
  for (int off = 1; off < 64; off <<= 1) lmax = fmaxf(lmax, __shfl_xor(lmax, off, 64));
  if ((threadIdx.x & 63) == 0) atomicMax(&mmL0[chunk], __float_as_uint(lmax));
  if (threadIdx.x == 0 && slice == 0) chunkScales[chunk] = smax;
}

// ---------------- tree: OUT[m] = IN[2m+1] * IN[2m], adaptively renormalized ----------------
__global__ __launch_bounds__(256) void tree_k(const unsigned short* __restrict__ in,
                                              unsigned short* __restrict__ out,
                                              const int* __restrict__ sIn,
                                              int* __restrict__ sOut,
                                              const unsigned* __restrict__ mmIn,
                                              unsigned* __restrict__ mmOut) {
  __shared__ float Al[64][65];
  __shared__ float Bl[64][65];
  int m = blockIdx.x >> 6;
  int t = blockIdx.x & 63;
  int i0 = (t >> 3) * 64, j0 = (t & 7) * 64;
  const unsigned short* A = in + (size_t)(2 * m + 1) * 262144;  // later chunk (left)
  const unsigned short* B = in + (size_t)(2 * m) * 262144;      // earlier chunk (right)
  int tid = threadIdx.x;
  int ty = tid >> 4, tx = tid & 15;

  // input exponents -> normalization so output entries stay ~[1, 2^13]
  int ea = (int)(mmIn[2 * m + 1] >> 23) - 127;
  int eb = (int)(mmIn[2 * m] >> 23) - 127;
  ea = max(min(ea, 60), -60); eb = max(min(eb, 60), -60);
  float norm = __uint_as_float((unsigned)(127 - ea - eb) << 23);

  float acc[4][4] = {};
#pragma unroll 1
  for (int k0 = 0; k0 < 512; k0 += 64) {
    __syncthreads();
    int r = tid >> 2, cs = (tid & 3) * 16;
    const unsigned short* ap = A + (size_t)(i0 + r) * 512 + k0 + cs;
    const unsigned short* bp = B + (size_t)(k0 + r) * 512 + j0 + cs;
#pragma unroll
    for (int q = 0; q < 16; ++q) Al[r][cs + q] = bf2f(ap[q]);
#pragma unroll
    for (int q = 0; q < 16; ++q) Bl[r][cs + q] = bf2f(bp[q]);
    __syncthreads();
#pragma unroll 8
    for (int k = 0; k < 64; ++k) {
      float av[4], bv[4];
#pragma unroll
      for (int i = 0; i < 4; ++i) av[i] = Al[ty * 4 + i][k];
#pragma unroll
      for (int j = 0; j < 4; ++j) bv[j] = Bl[k][tx * 4 + j];
#pragma unroll
      for (int i = 0; i < 4; ++i)
#pragma unroll
        for (int j = 0; j < 4; ++j) acc[i][j] += av[i] * bv[j];
    }
  }
  float lmax = 0.f;
#pragma unroll
  for (int i = 0; i < 4; ++i)
#pragma unroll
    for (int j = 0; j < 4; ++j) {
      float v = acc[i][j] * norm;
      lmax = fmaxf(lmax, v);
      out[(size_t)m * 262144 + (size_t)(i0 + ty * 4 + i) * 512 + (j0 + tx * 4 + j)] = f2bf(v);
    }
#pragma unroll
  for (int off = 1; off < 64; off <<= 1) lmax = fmaxf(lmax, __shfl_xor(lmax, off, 64));
  if ((tid & 63) == 0) atomicMax(&mmOut[m], __float_as_uint(lmax));
  if (t == 0 && tid == 0) sOut[m] = sIn[2 * m] + sIn[2 * m + 1] + ea + eb;
}

// ---------------- final: forward = log(sum P_total) + scale*ln2; out = fwd - gold ----------------
__global__ __launch_bounds__(512) void final_k(const unsigned short* __restrict__ P,
                                               const int* __restrict__ sc,
                                               const float* __restrict__ gpart,
                                               float* __restrict__ outp) {
  __shared__ float red[512];
  float s = 0.f;
  for (int i = threadIdx.x; i < 262144; i += 512) s += bf2f(P[i]);
  red[threadIdx.x] = s;
  __syncthreads();
  for (int h = 256; h > 0; h >>= 1) {
    if ((int)threadIdx.x < h) red[threadIdx.x] += red[threadIdx.x + h];
    __syncthreads();
  }
  if (threadIdx.x == 0) {
    double gold = 0.0;
    for (int q = 0; q < 32; ++q) gold += (double)gpart[q];
    double fwd = log((double)red[0]) + 0.69314718055994530942 * (double)sc[0];
    outp[0] = (float)(fwd - gold);
  }
}

extern "C" void kernel_launch(void* const* d_in, const int* in_sizes, int n_in,
                              void* d_out, int out_size, void* d_ws, size_t ws_size,
                              hipStream_t stream) {
  const float* obs = (const float*)d_in[0];   // (K, T) f32
  const int* tags = (const int*)d_in[1];      // (T,) i32
  const float* tr = (const float*)d_in[2];    // (K, K) f32
  float* out = (float*)d_out;

  uint8_t* ws = (uint8_t*)d_ws;
  uint8_t* Ehat = ws + OFF_EHAT;
  float* gpart = (float*)(ws + OFF_GPART);
  int* sliceScales = (int*)(ws + OFF_SSCAL);
  int* sc = (int*)(ws + OFF_SC);        // 64 ints, per-level
  unsigned* mm = (unsigned*)(ws + OFF_MM); // 64 uints, per-level
  unsigned short* matsA = (unsigned short*)(ws + OFF_MATS_A);
  unsigned short* matsB = (unsigned short*)(ws + OFF_MATS_B);

  hipLaunchKernelGGL(init_k, dim3(1), dim3(64), 0, stream, mm);
  hipLaunchKernelGGL(prep_e8_k, dim3(256), dim3(512), 0, stream, tr, Ehat);
  hipLaunchKernelGGL(gold_k, dim3(32), dim3(1024), 0, stream, obs, tags, tr, gpart);
  hipLaunchKernelGGL(phase1_k, dim3(256), dim3(512), 0, stream, Ehat, obs, matsA, sliceScales);
  hipLaunchKernelGGL(repair_k, dim3(256), dim3(256), 0, stream, matsA, sliceScales, sc + 0, mm + 0);
  // tree: 32 -> 16 -> 8 -> 4 -> 2 -> 1 (alternating matsA/matsB)
  hipLaunchKernelGGL(tree_k, dim3(16 * 64), dim3(256), 0, stream, matsA, matsB, sc + 0,  sc + 32, mm + 0,  mm + 32);
  hipLaunchKernelGGL(tree_k, dim3(8 * 64),  dim3(256), 0, stream, matsB, matsA, sc + 32, sc + 48, mm + 32, mm + 48);
  hipLaunchKernelGGL(tree_k, dim3(4 * 64),  dim3(256), 0, stream, matsA, matsB, sc + 48, sc + 56, mm + 48, mm + 56);
  hipLaunchKernelGGL(tree_k, dim3(2 * 64),  dim3(256), 0, stream, matsB, matsA, sc + 56, sc + 60, mm + 56, mm + 60);
  hipLaunchKernelGGL(tree_k, dim3(1 * 64),  dim3(256), 0, stream, matsA, matsB, sc + 60, sc + 62, mm + 60, mm + 62);
  hipLaunchKernelGGL(final_k, dim3(1), dim3(512), 0, stream, matsB, sc + 62, gpart, out);
}

// Round 3
// 3812.399 us; speedup vs baseline: 1.4808x; 1.4808x over previous
//
#include <hip/hip_runtime.h>
#include <cstdint>
#include <cstddef>

// Problem constants
#define K_ 512
#define T_ 32768
#define L_STEPS 1024   // T_/32 chunks

// workspace layout (bytes) -- total ~26 MB
#define OFF_EHAT   0ul         // 512*512 fp8 = 262144
#define OFF_GPART  262144ul    // 32 f32 gold partials
#define OFF_SSCAL  262400ul    // 256 int slice scales
#define OFF_SC     263424ul    // 64 int: per-level mat scales (L0@0 x32, L1@32 x16, L2@48 x8, L3@56 x4, L4@60 x2, L5@62 x1)
#define OFF_MM     263680ul    // 64 uint: per-level mat maxima (f32 bit patterns), same sub-offsets
#define OFF_MATS_A 1048576ul   // 32 mats * 512*512 bf16 = 16777216
#define OFF_MATS_B 17825792ul  // 16 mats bf16 = 8388608 (end 26214400)

typedef float f32x4 __attribute__((ext_vector_type(4)));
typedef int i32x4 __attribute__((ext_vector_type(4)));
typedef int i32x8 __attribute__((ext_vector_type(8)));

static __device__ __forceinline__ unsigned short f2bf(float x) {
  unsigned u = __float_as_uint(x);
  u += 0x7fffu + ((u >> 16) & 1u);
  return (unsigned short)(u >> 16);
}
static __device__ __forceinline__ float bf2f(unsigned short h) {
  return __uint_as_float(((unsigned)h) << 16);
}
static __device__ __forceinline__ i32x8 lds_ld32(const uint8_t* p) {
  i32x4 lo = *(const i32x4*)p;          // ds_read_b128 (16B-aligned)
  i32x4 hi = *(const i32x4*)(p + 16);
  return __builtin_shufflevector(lo, hi, 0, 1, 2, 3, 4, 5, 6, 7);
}

// ---------------- init: zero the atomic-max slots ----------------
__global__ __launch_bounds__(64) void init_k(unsigned* __restrict__ mm) {
  mm[threadIdx.x] = 0u;
}

// ---------------- prep: Ehat = fp8_e4m3(exp(transitions)) ----------------
__global__ __launch_bounds__(512) void prep_e8_k(const float* __restrict__ tr,
                                                 uint8_t* __restrict__ Ehat) {
  int gid = blockIdx.x * 512 + threadIdx.x;   // 131072 threads, 2 elems each
  int i2 = gid * 2;
  float a = fminf(__expf(tr[i2]), 440.f);
  float b = fminf(__expf(tr[i2 + 1]), 440.f);
  int w = __builtin_amdgcn_cvt_pk_fp8_f32(a, b, 0, false);
  *(unsigned short*)(Ehat + i2) = (unsigned short)(w & 0xffff);
}

// ---------------- gold score (exact f32, deterministic, 32 partials) ----------------
__global__ __launch_bounds__(1024) void gold_k(const float* __restrict__ obs,
                                               const int* __restrict__ tags,
                                               const float* __restrict__ tr,
                                               float* __restrict__ gpart) {
  __shared__ float red[1024];
  int i = blockIdx.x * 1024 + threadIdx.x;
  float s = 0.f;
  if (i < T_ - 1) {
    int cur = tags[i], nxt = tags[i + 1];
    s = tr[nxt * K_ + cur] + obs[(size_t)nxt * T_ + i];
  }
  red[threadIdx.x] = s;
  __syncthreads();
  for (int h = 512; h > 0; h >>= 1) {
    if ((int)threadIdx.x < h) red[threadIdx.x] += red[threadIdx.x + h];
    __syncthreads();
  }
  if (threadIdx.x == 0) gpart[blockIdx.x] = red[0];
}

// ---------------- phase 1: per-(chunk, 64-col slice) transfer matrix ----------------
// wg = 512 threads (8 waves). Wave wv owns output rows 64wv..64wv+63; E rows resident
// as fp8 MX-MFMA A-fragments (16 x i32x8 = 128 VGPR). P slice (512 x 64) lives in LDS
// transposed: PldsT[col][k], row stride 528 bytes (16B aligned for ds_read_b128).
// Per step: acc = E * P via mfma_scale_f32_16x16x128_f8f6f4 (neutral E8M0 scales),
// 64 MFMA/wave; then acc *= exp(o_t[row]); power-of-2 renorm to max in [128,256);
// store fp8. Block remap: a chunk's 8 slices land on one XCD (shared L2 for obs).
__global__ __launch_bounds__(512, 2)
void phase1_k(const uint8_t* __restrict__ Ehat, const float* __restrict__ obs,
              unsigned short* __restrict__ mats, int* __restrict__ sliceScales) {
  __shared__ __align__(16) uint8_t Plds[64 * 528];   // 33792 B
  __shared__ float obs_lds[8][512];                  // 16384 B
  __shared__ float wavemax[8];

  const int tid = threadIdx.x;
  const int wv = tid >> 6;
  const int lane = tid & 63;
  const int l15 = lane & 15;
  const int g = lane >> 4;
  // XCD-aware remap: chunk c's 8 slices all have bid%8 == c%... (same XCD)
  const int bid = blockIdx.x;
  const int chunk = 4 * (bid & 7) + (bid >> 6);
  const int slice = (bid >> 3) & 7;

  // E fragments for 16x16x128: lane holds A[row=l15][k=32g..32g+31] per (rt, kt)
  i32x8 ef[4][4];
#pragma unroll
  for (int rt = 0; rt < 4; ++rt)
#pragma unroll
    for (int kt = 0; kt < 4; ++kt)
      ef[rt][kt] = *(const i32x8*)(Ehat +
          ((64 * wv + 16 * rt + l15) * 512 + 128 * kt + 32 * g));

  // init P = identity slice
  for (int i = tid; i < 64 * 528 / 4; i += 512) ((int*)Plds)[i] = 0;
  __syncthreads();
  if (tid < 64) {
    int gj = slice * 64 + tid;          // global state index of this column
    Plds[tid * 528 + gj] = 0x38;        // fp8 e4m3 1.0
  }
  __syncthreads();

  int accScale = 0;
  const int t0 = chunk * L_STEPS;

  // obs prefetch registers (8 timesteps of this thread's row)
  float4 pf0, pf1;
  {
    const float4* sp = (const float4*)(obs + (size_t)tid * T_ + t0);
    pf0 = sp[0]; pf1 = sp[1];
  }

#pragma unroll 1
  for (int tl = 0; tl < L_STEPS; ++tl) {
    if ((tl & 7) == 0) {
      obs_lds[0][tid] = pf0.x; obs_lds[1][tid] = pf0.y;
      obs_lds[2][tid] = pf0.z; obs_lds[3][tid] = pf0.w;
      obs_lds[4][tid] = pf1.x; obs_lds[5][tid] = pf1.y;
      obs_lds[6][tid] = pf1.z; obs_lds[7][tid] = pf1.w;
      __syncthreads();
      // issue next prefetch AFTER the barrier: latency hides under this step's MFMA
      int tn = t0 + tl + 8;
      if (tn >= T_) tn = 0;             // dummy (last block of last chunk)
      const float4* sp = (const float4*)(obs + (size_t)tid * T_ + tn);
      pf0 = sp[0]; pf1 = sp[1];
    }

    f32x4 acc[4][4];
#pragma unroll
    for (int rt = 0; rt < 4; ++rt)
#pragma unroll
      for (int ct = 0; ct < 4; ++ct) acc[rt][ct] = (f32x4){0.f, 0.f, 0.f, 0.f};

#pragma unroll
    for (int kt = 0; kt < 4; ++kt) {
      const uint8_t* pb = Plds + 128 * kt + 32 * g;
      i32x8 b0 = lds_ld32(pb + (l15)      * 528);
      i32x8 b1 = lds_ld32(pb + (16 + l15) * 528);
      i32x8 b2 = lds_ld32(pb + (32 + l15) * 528);
      i32x8 b3 = lds_ld32(pb + (48 + l15) * 528);
#pragma unroll
      for (int rt = 0; rt < 4; ++rt) {
        acc[rt][0] = __builtin_amdgcn_mfma_scale_f32_16x16x128_f8f6f4(
            ef[rt][kt], b0, acc[rt][0], 0, 0, 0, 0x7f7f7f7f, 0, 0x7f7f7f7f);
        acc[rt][1] = __builtin_amdgcn_mfma_scale_f32_16x16x128_f8f6f4(
            ef[rt][kt], b1, acc[rt][1], 0, 0, 0, 0x7f7f7f7f, 0, 0x7f7f7f7f);
        acc[rt][2] = __builtin_amdgcn_mfma_scale_f32_16x16x128_f8f6f4(
            ef[rt][kt], b2, acc[rt][2], 0, 0, 0, 0x7f7f7f7f, 0, 0x7f7f7f7f);
        acc[rt][3] = __builtin_amdgcn_mfma_scale_f32_16x16x128_f8f6f4(
            ef[rt][kt], b3, acc[rt][3], 0, 0, 0, 0x7f7f7f7f, 0, 0x7f7f7f7f);
      }
    }

    // epilogue: row scale by exp(o_t) in place, power-of-2 renorm, fp8 store
    const int tl7 = tl & 7;
    float eo[4][4];
#pragma unroll
    for (int rt = 0; rt < 4; ++rt)
#pragma unroll
      for (int j = 0; j < 4; ++j)
        eo[rt][j] = __expf(obs_lds[tl7][64 * wv + 16 * rt + 4 * g + j]);

    float mx = 0.f;
#pragma unroll
    for (int rt = 0; rt < 4; ++rt)
#pragma unroll
      for (int ct = 0; ct < 4; ++ct)
#pragma unroll
        for (int j = 0; j < 4; ++j) {
          acc[rt][ct][j] *= eo[rt][j];
          mx = fmaxf(mx, acc[rt][ct][j]);
        }
#pragma unroll
    for (int off = 1; off < 64; off <<= 1) mx = fmaxf(mx, __shfl_xor(mx, off, 64));
    if (lane == 0) wavemax[wv] = mx;
    __syncthreads();   // also: all P reads (B-frags) complete before overwrite

    float m8 = wavemax[0];
#pragma unroll
    for (int q = 1; q < 8; ++q) m8 = fmaxf(m8, wavemax[q]);
    int ebits = (int)((__float_as_uint(m8) >> 23) & 255) - 127;
    int s = 7 - ebits;
    if (s < -120) s = -120;
    if (s > 120) s = 120;
    float scale = __uint_as_float((unsigned)(127 + s) << 23);
    accScale -= s;     // TRUE = stored * 2^accScale

#pragma unroll
    for (int rt = 0; rt < 4; ++rt)
#pragma unroll
      for (int ct = 0; ct < 4; ++ct) {
        float v0 = acc[rt][ct][0] * scale;
        float v1 = acc[rt][ct][1] * scale;
        float v2 = acc[rt][ct][2] * scale;
        float v3 = acc[rt][ct][3] * scale;
        int w32 = __builtin_amdgcn_cvt_pk_fp8_f32(v0, v1, 0, false);
        w32 = __builtin_amdgcn_cvt_pk_fp8_f32(v2, v3, w32, true);
        // rows 4 consecutive (4g..4g+3), col = 16ct+l15
        *(int*)(Plds + (16 * ct + l15) * 528 + (64 * wv + 16 * rt + 4 * g)) = w32;
      }
    __syncthreads();
  }

  // write slice (bf16) to chunk matrix, row-major [i][j]
  for (int cl = 0; cl < 64; ++cl) {
    float f = __builtin_amdgcn_cvt_f32_fp8((int)Plds[cl * 528 + tid], 0);
    mats[(size_t)chunk * 262144 + (size_t)tid * 512 + slice * 64 + cl] = f2bf(f);
  }
  if (tid == 0) sliceScales[chunk * 8 + slice] = accScale;
}

// ---------------- repair: harmonize the 8 slice scales of each chunk; record chunk max ----------------
__global__ __launch_bounds__(256) void repair_k(unsigned short* __restrict__ mats,
                                                const int* __restrict__ sliceScales,
                                                int* __restrict__ chunkScales,
                                                unsigned* __restrict__ mmL0) {
  int chunk = blockIdx.x >> 3, slice = blockIdx.x & 7;
  int smax = sliceScales[chunk * 8];
  for (int q = 1; q < 8; ++q) smax = max(smax, sliceScales[chunk * 8 + q]);
  int d = sliceScales[chunk * 8 + slice] - smax;   // <= 0
  float fac = exp2f((float)max(d, -126));
  float lmax = 0.f;
  for (int n = threadIdx.x; n < 512 * 64; n += 256) {
    int row = n >> 6, col = n & 63;
    size_t idx = (size_t)chunk * 262144 + (size_t)row * 512 + slice * 64 + col;
    float v = bf2f(mats[idx]) * fac;
    mats[idx] = f2bf(v);
    lmax = fmaxf(lmax, v);
  }
#pragma unroll
  for (int off = 1; off < 64; off <<= 1) lmax = fmaxf(lmax, __shfl_xor(lmax, off, 64));
  if ((threadIdx.x & 63) == 0) atomicMax(&mmL0[chunk], __float_as_uint(lmax));
  if (threadIdx.x == 0 && slice == 0) chunkScales[chunk] = smax;
}

// ---------------- tree: OUT[m] = IN[2m+1] * IN[2m], adaptively renormalized ----------------
__global__ __launch_bounds__(256) void tree_k(const unsigned short* __restrict__ in,
                                              unsigned short* __restrict__ out,
                                              const int* __restrict__ sIn,
                                              int* __restrict__ sOut,
                                              const unsigned* __restrict__ mmIn,
                                              unsigned* __restrict__ mmOut) {
  __shared__ float Al[64][65];
  __shared__ float Bl[64][65];
  int m = blockIdx.x >> 6;
  int t = blockIdx.x & 63;
  int i0 = (t >> 3) * 64, j0 = (t & 7) * 64;
  const unsigned short* A = in + (size_t)(2 * m + 1) * 262144;  // later chunk (left)
  const unsigned short* B = in + (size_t)(2 * m) * 262144;      // earlier chunk (right)
  int tid = threadIdx.x;
  int ty = tid >> 4, tx = tid & 15;

  // input exponents -> normalization so output entries stay ~[1, 2^13]
  int ea = (int)(mmIn[2 * m + 1] >> 23) - 127;
  int eb = (int)(mmIn[2 * m] >> 23) - 127;
  ea = max(min(ea, 60), -60); eb = max(min(eb, 60), -60);
  float norm = __uint_as_float((unsigned)(127 - ea - eb) << 23);

  float acc[4][4] = {};
#pragma unroll 1
  for (int k0 = 0; k0 < 512; k0 += 64) {
    __syncthreads();
    int r = tid >> 2, cs = (tid & 3) * 16;
    const unsigned short* ap = A + (size_t)(i0 + r) * 512 + k0 + cs;
    const unsigned short* bp = B + (size_t)(k0 + r) * 512 + j0 + cs;
#pragma unroll
    for (int q = 0; q < 16; ++q) Al[r][cs + q] = bf2f(ap[q]);
#pragma unroll
    for (int q = 0; q < 16; ++q) Bl[r][cs + q] = bf2f(bp[q]);
    __syncthreads();
#pragma unroll 8
    for (int k = 0; k < 64; ++k) {
      float av[4], bv[4];
#pragma unroll
      for (int i = 0; i < 4; ++i) av[i] = Al[ty * 4 + i][k];
#pragma unroll
      for (int j = 0; j < 4; ++j) bv[j] = Bl[k][tx * 4 + j];
#pragma unroll
      for (int i = 0; i < 4; ++i)
#pragma unroll
        for (int j = 0; j < 4; ++j) acc[i][j] += av[i] * bv[j];
    }
  }
  float lmax = 0.f;
#pragma unroll
  for (int i = 0; i < 4; ++i)
#pragma unroll
    for (int j = 0; j < 4; ++j) {
      float v = acc[i][j] * norm;
      lmax = fmaxf(lmax, v);
      out[(size_t)m * 262144 + (size_t)(i0 + ty * 4 + i) * 512 + (j0 + tx * 4 + j)] = f2bf(v);
    }
#pragma unroll
  for (int off = 1; off < 64; off <<= 1) lmax = fmaxf(lmax, __shfl_xor(lmax, off, 64));
  if ((tid & 63) == 0) atomicMax(&mmOut[m], __float_as_uint(lmax));
  if (t == 0 && tid == 0) sOut[m] = sIn[2 * m] + sIn[2 * m + 1] + ea + eb;
}

// ---------------- final: forward = log(sum P_total) + scale*ln2; out = fwd - gold ----------------
__global__ __launch_bounds__(512) void final_k(const unsigned short* __restrict__ P,
                                               const int* __restrict__ sc,
                                               const float* __restrict__ gpart,
                                               float* __restrict__ outp) {
  __shared__ float red[512];
  float s = 0.f;
  for (int i = threadIdx.x; i < 262144; i += 512) s += bf2f(P[i]);
  red[threadIdx.x] = s;
  __syncthreads();
  for (int h = 256; h > 0; h >>= 1) {
    if ((int)threadIdx.x < h) red[threadIdx.x] += red[threadIdx.x + h];
    __syncthreads();
  }
  if (threadIdx.x == 0) {
    double gold = 0.0;
    for (int q = 0; q < 32; ++q) gold += (double)gpart[q];
    double fwd = log((double)red[0]) + 0.69314718055994530942 * (double)sc[0];
    outp[0] = (float)(fwd - gold);
  }
}

extern "C" void kernel_launch(void* const* d_in, const int* in_sizes, int n_in,
                              void* d_out, int out_size, void* d_ws, size_t ws_size,
                              hipStream_t stream) {
  const float* obs = (const float*)d_in[0];   // (K, T) f32
  const int* tags = (const int*)d_in[1];      // (T,) i32
  const float* tr = (const float*)d_in[2];    // (K, K) f32
  float* out = (float*)d_out;

  uint8_t* ws = (uint8_t*)d_ws;
  uint8_t* Ehat = ws + OFF_EHAT;
  float* gpart = (float*)(ws + OFF_GPART);
  int* sliceScales = (int*)(ws + OFF_SSCAL);
  int* sc = (int*)(ws + OFF_SC);           // 64 ints, per-level
  unsigned* mm = (unsigned*)(ws + OFF_MM); // 64 uints, per-level
  unsigned short* matsA = (unsigned short*)(ws + OFF_MATS_A);
  unsigned short* matsB = (unsigned short*)(ws + OFF_MATS_B);

  hipLaunchKernelGGL(init_k, dim3(1), dim3(64), 0, stream, mm);
  hipLaunchKernelGGL(prep_e8_k, dim3(256), dim3(512), 0, stream, tr, Ehat);
  hipLaunchKernelGGL(gold_k, dim3(32), dim3(1024), 0, stream, obs, tags, tr, gpart);
  hipLaunchKernelGGL(phase1_k, dim3(256), dim3(512), 0, stream, Ehat, obs, matsA, sliceScales);
  hipLaunchKernelGGL(repair_k, dim3(256), dim3(256), 0, stream, matsA, sliceScales, sc + 0, mm + 0);
  // tree: 32 -> 16 -> 8 -> 4 -> 2 -> 1 (alternating matsA/matsB)
  hipLaunchKernelGGL(tree_k, dim3(16 * 64), dim3(256), 0, stream, matsA, matsB, sc + 0,  sc + 32, mm + 0,  mm + 32);
  hipLaunchKernelGGL(tree_k, dim3(8 * 64),  dim3(256), 0, stream, matsB, matsA, sc + 32, sc + 48, mm + 32, mm + 48);
  hipLaunchKernelGGL(tree_k, dim3(4 * 64),  dim3(256), 0, stream, matsA, matsB, sc + 48, sc + 56, mm + 48, mm + 56);
  hipLaunchKernelGGL(tree_k, dim3(2 * 64),  dim3(256), 0, stream, matsB, matsA, sc + 56, sc + 60, mm + 56, mm + 60);
  hipLaunchKernelGGL(tree_k, dim3(1 * 64),  dim3(256), 0, stream, matsA, matsB, sc + 60, sc + 62, mm + 60, mm + 62);
  hipLaunchKernelGGL(final_k, dim3(1), dim3(512), 0, stream, matsB, sc + 62, gpart, out);
}